// Round 1
// baseline (185.230 us; speedup 1.0000x reference)
//
#include <hip/hip_runtime.h>
#include <hip/hip_bf16.h>

// Problem constants (from reference)
#define B_   256
#define M_   64
#define T_   1200
#define FT_  10
#define K_   17
#define PAD_ 8
#define POOLK_ 75
#define POOLS_ 15
#define TP_  76           // pooled length
#define NSEG_ 80          // T_/POOLS_ segments of 15
#define NPAIR_ (FT_*NSEG_) // 800
#define FEAT_ (FT_*TP_)    // 760

__global__ __launch_bounds__(256)
void ChannelScorer_Distributed_39024072851482_kernel(
    const float* __restrict__ x,      // (B,1,M,T) -> row-major (B*M, T)
    const float* __restrict__ conv_w, // (FT,1,K) = 170
    const float* __restrict__ conv_b, // (FT,)
    const float* __restrict__ lin_w,  // (M, FEAT)
    const float* __restrict__ lin_b,  // (M,)
    float* __restrict__ out)          // (B,M,1) -> 16384
{
    __shared__ float xs[T_ + 2*PAD_];   // 1216 padded row
    __shared__ float wsm[FT_*K_];       // 170
    __shared__ float bsm[FT_];          // 10
    __shared__ float S[NPAIR_];         // 800 segment sums of squared conv
    __shared__ float red[4];

    const int row = blockIdx.x;          // b*M_+m
    const int m   = row & (M_-1);
    const int tid = threadIdx.x;

    // ---- stage x row into LDS (padded with zeros) ----
    if (tid < PAD_)  xs[tid] = 0.f;
    if (tid >= 256-PAD_) xs[tid + (T_ + PAD_ - (256-PAD_))] = 0.f; // 1208..1215
    {
        const float4* xr = (const float4*)(x + (size_t)row * T_); // 4800B row, 16B aligned
        for (int i = tid; i < T_/4; i += 256)
            *(float4*)&xs[PAD_ + 4*i] = xr[i];
    }
    for (int i = tid; i < FT_*K_; i += 256) wsm[i] = conv_w[i];
    if (tid < FT_) bsm[tid] = conv_b[tid];
    __syncthreads();

    // ---- conv + square + segment-sum: 800 (f,g) pairs ----
    for (int pair = tid; pair < NPAIR_; pair += 256) {
        const int f = pair / NSEG_;       // 0..9
        const int g = pair - f*NSEG_;     // 0..79
        float w[K_];
        #pragma unroll
        for (int k = 0; k < K_; ++k) w[k] = wsm[f*K_ + k];
        const float bf = bsm[f];

        float xv[POOLS_ + K_ - 1];        // 31 values
        const int base = POOLS_ * g;
        #pragma unroll
        for (int j = 0; j < POOLS_ + K_ - 1; ++j) xv[j] = xs[base + j];

        float seg = 0.f;
        #pragma unroll
        for (int j = 0; j < POOLS_; ++j) {
            float acc = bf;
            #pragma unroll
            for (int k = 0; k < K_; ++k)
                acc = fmaf(xv[j + k], w[k], acc);
            seg = fmaf(acc, acc, seg);
        }
        S[pair] = seg;
    }
    __syncthreads();

    // ---- pooled -> log -> dot with lin_w[m,:] ----
    float partial = 0.f;
    const float* lw = lin_w + m * FEAT_;
    for (int i = tid; i < FEAT_; i += 256) {
        const int f = i / TP_;            // 0..9
        const int p = i - f * TP_;        // 0..75
        const float* Sp = &S[f*NSEG_ + p];
        float v = (Sp[0] + Sp[1] + Sp[2] + Sp[3] + Sp[4]) * (1.0f/POOLK_);
        v = fmaxf(v, 1e-10f);
        partial = fmaf(__logf(v), lw[i], partial);
    }

    // ---- block reduction ----
    #pragma unroll
    for (int off = 32; off > 0; off >>= 1)
        partial += __shfl_down(partial, off, 64);
    const int wave = tid >> 6, lane = tid & 63;
    if (lane == 0) red[wave] = partial;
    __syncthreads();
    if (tid == 0)
        out[row] = red[0] + red[1] + red[2] + red[3] + lin_b[m];
}

extern "C" void kernel_launch(void* const* d_in, const int* in_sizes, int n_in,
                              void* d_out, int out_size, void* d_ws, size_t ws_size,
                              hipStream_t stream) {
    const float* x      = (const float*)d_in[0];
    const float* conv_w = (const float*)d_in[1];
    const float* conv_b = (const float*)d_in[2];
    const float* lin_w  = (const float*)d_in[3];
    const float* lin_b  = (const float*)d_in[4];
    float* out = (float*)d_out;

    dim3 grid(B_ * M_);
    dim3 block(256);
    ChannelScorer_Distributed_39024072851482_kernel<<<grid, block, 0, stream>>>(
        x, conv_w, conv_b, lin_w, lin_b, out);
}